// Round 1
// baseline (463.785 us; speedup 1.0000x reference)
//
#include <hip/hip_runtime.h>
#include <hip/hip_bf16.h>

// Problem: out[n,o] = x[n,:] . W[o,:] + bias[o] + scale * sum_r (x[n,:].la[a,r,:]) * lb[a,o,:][r]
//          where a = lora_mapping[n]-1 (skip if mapping==0).
// Strategy: fold LoRA into the GEMM K-dim. Build bf16 Xe[16384,2176], We[2048,2176]
//   Xe[:,0:2048]=bf16(x); Xe[n,2048+(a*16+r)] = bf16(scale * x[n].la[a,r])  (one-hot in a)
//   We[:,0:2048]=bf16(W); We[o,2048+(a*16+r)] = bf16(lb[a,o,r])
// Then out = Xe @ We^T + bias — a single uniform bf16 MFMA GEMM, K=2176=34*64.
//
// R1: prep_x scalar+shuffle version latency-bound (154us).
// R2 FAILED: 16 parallel accumulators spilled to scratch -> 231us.
// R3: u via MFMA for ALL adapters, mask in epilogue. 456us total.
// R4 (this round): prep_x_mfma was latency-bound (HBM 12%, Mfma 2%, VALU 9%) at
//   145us. Split into regime-pure kernels:
//   - conv_all: pure streaming fp32->bf16 of x AND W (Xe/We contiguous in ws,
//     same row-convert with KEXT stride). 226 MB -> ~40us at BW.
//   - ext_mfma: u = Xb(bf16) @ La^T, reading bf16 (half the bytes of fp32 x).
//     8 waves/block, wave w owns adapter w's 16 cols (mask is wave-uniform).
//   - ext_w: tiny streaming lora_b extension write (absorbs old prep_w ext).
//   gemm_fused untouched (1007 TF effective; 256^2 8-phase rewrite is next).

#define D_IN   2048
#define D_OUT  2048
#define NTOK   16384
#define RANK   16
#define NADAPT 8
#define KEXT   2176          // 2048 + 8*16
#define BM     128
#define BN     128
#define BK     64
#define NROWS  (NTOK + D_OUT)   // rows to convert in conv_all

typedef __attribute__((ext_vector_type(8))) __bf16 bf16x8;
typedef __attribute__((ext_vector_type(8))) unsigned short u16x8;
typedef __attribute__((ext_vector_type(4))) float  f32x4;

__device__ inline unsigned short f2bf(float f) {
    unsigned u = __builtin_bit_cast(unsigned, f);
    u += 0x7fffu + ((u >> 16) & 1u);      // round-to-nearest-even
    return (unsigned short)(u >> 16);
}

// ---------------------------------------------------------------------------
// conv_la: lora_a [8][16][2048] fp32 -> La [128][2048] bf16 (512 KB, L2-hot).
// ---------------------------------------------------------------------------
__global__ void conv_la(const float4* __restrict__ la, ushort4* __restrict__ La) {
    int t = blockIdx.x * 256 + threadIdx.x;
    float4 v = la[t];
    ushort4 s;
    s.x = f2bf(v.x); s.y = f2bf(v.y); s.z = f2bf(v.z); s.w = f2bf(v.w);
    La[t] = s;
}

// ---------------------------------------------------------------------------
// conv_all: streaming fp32->bf16 for x (rows 0..16383) and W (rows 16384..18431).
// Xe and We are contiguous in workspace and share KEXT row stride, so one
// grid-stride loop covers both. 32B/lane read, 16B/lane write, fully coalesced.
// ---------------------------------------------------------------------------
__global__ void conv_all(const float* __restrict__ x, const float* __restrict__ w,
                         unsigned short* __restrict__ XeWe) {
    const size_t TOTAL = (size_t)NROWS * (D_IN / 8);    // float8 units
    size_t stride = (size_t)gridDim.x * blockDim.x;
    for (size_t u = (size_t)blockIdx.x * blockDim.x + threadIdx.x; u < TOTAL; u += stride) {
        int n  = (int)(u >> 8);                          // 256 units per row
        int kc = ((int)u & 255) * 8;
        const float* src = (n < NTOK) ? x + (size_t)n * D_IN + kc
                                      : w + (size_t)(n - NTOK) * D_IN + kc;
        float4 v0 = *(const float4*)(src);
        float4 v1 = *(const float4*)(src + 4);
        u16x8 s;
        s[0] = f2bf(v0.x); s[1] = f2bf(v0.y); s[2] = f2bf(v0.z); s[3] = f2bf(v0.w);
        s[4] = f2bf(v1.x); s[5] = f2bf(v1.y); s[6] = f2bf(v1.z); s[7] = f2bf(v1.w);
        *(u16x8*)(XeWe + (size_t)n * KEXT + kc) = s;
    }
}

// ---------------------------------------------------------------------------
// ext_w: We extension columns. We[o, 2048 + a*16 + r] = bf16(lb[a,o,r]).
// 2048*128 elements, pure streaming.
// ---------------------------------------------------------------------------
__global__ void ext_w(const float* __restrict__ lora_b, unsigned short* __restrict__ We) {
    int t = blockIdx.x * 256 + threadIdx.x;              // 262144 threads
    int o = t >> 7, c = t & 127;
    int a = c >> 4, r = c & 15;
    We[(size_t)o * KEXT + D_IN + c] = f2bf(lora_b[((size_t)a * D_OUT + o) * RANK + r]);
}

// ---------------------------------------------------------------------------
// ext_mfma: u[n][c] = Xb[n,:] . La[c,:] for all 128 ext cols, mask by the
// token's adapter, scale, write Xe[:, 2048+c]. Reads the bf16 Xb written by
// conv_all (67 MB, half of re-reading fp32 x). 512 blocks x 512 threads:
// block = 32 tokens, wave w (0..7) owns cols w*16..w*16+15 == adapter w
// exactly, so mask/scale are wave-uniform. acc[2] (two 16-token row tiles),
// 3 global loads + 2 MFMAs per K=32 step. All 8 waves load identical A
// addresses -> L1 broadcast. 16 waves/CU.
// u C-layout: col=lane&15 (ext col), row=(lane>>4)*4+reg (token) [m89-verified].
// Reads cols 0..2047, writes cols 2048.. — disjoint, no hazard.
// ---------------------------------------------------------------------------
__global__ void ext_mfma(unsigned short* Xe, const int* __restrict__ map,
                         const unsigned short* __restrict__ La,
                         const float* __restrict__ scaling) {
    int t = threadIdx.x, lane = t & 63, wave = t >> 6;   // wave 0..7
    int n0 = blockIdx.x * 32;
    int arow = lane & 15;                                // token (A) / ext col (B) row
    int kq   = lane >> 4;                                // k-offset quarter

    f32x4 acc[2] = {};

    const unsigned short* xr0 = Xe + (size_t)(n0 + arow) * KEXT + kq * 8;
    const unsigned short* xr1 = xr0 + (size_t)16 * KEXT;
    const unsigned short* lb  = La + (size_t)(wave * 16 + arow) * D_IN + kq * 8;

#pragma unroll 4
    for (int k0 = 0; k0 < D_IN; k0 += 32) {
        bf16x8 a0 = *(const bf16x8*)(xr0 + k0);
        bf16x8 a1 = *(const bf16x8*)(xr1 + k0);
        bf16x8 b  = *(const bf16x8*)(lb + k0);
        acc[0] = __builtin_amdgcn_mfma_f32_16x16x32_bf16(a0, b, acc[0], 0, 0, 0);
        acc[1] = __builtin_amdgcn_mfma_f32_16x16x32_bf16(a1, b, acc[1], 0, 0, 0);
    }

    // epilogue: wave w == adapter w; mask tokens whose mapping != w+1
    int colq = lane & 15, rq = lane >> 4;
    int c = wave * 16 + colq;                            // ext col
    float sc = scaling[wave];
#pragma unroll
    for (int i = 0; i < 2; ++i) {
#pragma unroll
        for (int r = 0; r < 4; ++r) {
            int token = n0 + i * 16 + rq * 4 + r;
            unsigned short v = 0;
            if (map[token] == wave + 1) v = f2bf(acc[i][r] * sc);
            Xe[(size_t)token * KEXT + D_IN + c] = v;
        }
    }
}

// ---------------------------------------------------------------------------
// Main GEMM: out[M=16384, N=2048] = Xe @ We^T + bias.  m97 structure:
// 128x128 tile, BK=64, 4 waves in 2x2, each wave 64x64 via 4x4 of 16x16x32
// bf16 MFMA, global_load_lds width=16 staging, XOR-swizzled LDS k-chunks
// (swizzle applied on the global source address so the wave-uniform LDS
// destination stays contiguous — required by global_load_lds semantics).
// ---------------------------------------------------------------------------
__global__ void gemm_fused(const unsigned short* __restrict__ Xe,
                           const unsigned short* __restrict__ We,
                           const float* __restrict__ bias,
                           float* __restrict__ out) {
    __shared__ unsigned short As[BM * BK];               // [128][64] bf16, 16 KB
    __shared__ unsigned short Bs[BN * BK];

    int t = threadIdx.x;
    int lane = t & 63, wave = t >> 6;
    // supertile swizzle: groups of 8 row-tiles x 16 col-tiles for L2 locality
    int g = blockIdx.x;
    int group = g >> 7, within = g & 127;
    int bm = group * 8 + (within & 7);                   // 0..127
    int bn = within >> 3;                                // 0..15

    int wm = wave >> 1, wn = wave & 1;                   // 2x2 wave grid
    f32x4 acc[4][4] = {};

    for (int k0 = 0; k0 < KEXT; k0 += BK) {
        __syncthreads();                                 // prev compute done
#pragma unroll
        for (int c = 0; c < 4; ++c) {
            int linear = (wave * 4 + c) * 64 + lane;     // 16B-chunk id within tile
            int row = linear >> 3;                       // 0..127
            int kc  = linear & 7;                        // 16B chunk within row
            int gc  = kc ^ (row & 7);                    // fetch swizzled source chunk
            const unsigned short* ga = Xe + (size_t)(bm * BM + row) * KEXT + k0 + gc * 8;
            __builtin_amdgcn_global_load_lds(
                (const __attribute__((address_space(1))) unsigned int*)ga,
                (__attribute__((address_space(3))) unsigned int*)(As + (wave * 4 + c) * 512),
                16, 0, 0);
            const unsigned short* gb = We + (size_t)(bn * BN + row) * KEXT + k0 + gc * 8;
            __builtin_amdgcn_global_load_lds(
                (const __attribute__((address_space(1))) unsigned int*)gb,
                (__attribute__((address_space(3))) unsigned int*)(Bs + (wave * 4 + c) * 512),
                16, 0, 0);
        }
        __syncthreads();                                 // staging visible (compiler drains vmcnt)
#pragma unroll
        for (int ks = 0; ks < 2; ++ks) {                 // two K=32 steps per BK=64
            bf16x8 af[4], bfr[4];
            int gchunk = ks * 4 + (lane >> 4);
            int sw = gchunk ^ (lane & 7);                // row&7 == lane&7 for 16-aligned tiles
#pragma unroll
            for (int i = 0; i < 4; ++i) {
                int rowA = wm * 64 + i * 16 + (lane & 15);
                af[i]  = *(const bf16x8*)(As + rowA * BK + sw * 8);
                int rowB = wn * 64 + i * 16 + (lane & 15);
                bfr[i] = *(const bf16x8*)(Bs + rowB * BK + sw * 8);
            }
#pragma unroll
            for (int i = 0; i < 4; ++i)
#pragma unroll
                for (int j = 0; j < 4; ++j)
                    acc[i][j] = __builtin_amdgcn_mfma_f32_16x16x32_bf16(af[i], bfr[j], acc[i][j], 0, 0, 0);
        }
    }

    // epilogue: C/D layout col=lane&15, row=(lane>>4)*4+reg  [m89-verified]
    int colq = lane & 15, rq = lane >> 4;
#pragma unroll
    for (int j = 0; j < 4; ++j) {
        int col = bn * BN + wn * 64 + j * 16 + colq;
        float bv = bias[col];
#pragma unroll
        for (int i = 0; i < 4; ++i) {
            int row0 = bm * BM + wm * 64 + i * 16 + rq * 4;
#pragma unroll
            for (int r = 0; r < 4; ++r)
                out[(size_t)(row0 + r) * D_OUT + col] = acc[i][j][r] + bv;
        }
    }
}

extern "C" void kernel_launch(void* const* d_in, const int* in_sizes, int n_in,
                              void* d_out, int out_size, void* d_ws, size_t ws_size,
                              hipStream_t stream) {
    (void)in_sizes; (void)n_in; (void)out_size; (void)ws_size;
    const float* x       = (const float*)d_in[0];
    const int*   map     = (const int*)d_in[1];
    const float* weight  = (const float*)d_in[2];
    const float* bias    = (const float*)d_in[3];
    const float* lora_a  = (const float*)d_in[4];
    const float* lora_b  = (const float*)d_in[5];
    const float* scaling = (const float*)d_in[6];
    float* out = (float*)d_out;

    unsigned short* Xe = (unsigned short*)d_ws;                    // 16384*2176*2 = 71.3 MB
    unsigned short* We = Xe + (size_t)NTOK * KEXT;                 // + 8.9 MB
    unsigned short* La = We + (size_t)D_OUT * KEXT;                // + 0.5 MB bf16 [128][2048]

    conv_la<<<256, 256, 0, stream>>>((const float4*)lora_a, (ushort4*)La);
    conv_all<<<2304, 256, 0, stream>>>(x, weight, Xe);             // x + W in one stream pass
    ext_w<<<1024, 256, 0, stream>>>(lora_b, We);
    ext_mfma<<<NTOK / 32, 512, 0, stream>>>(Xe, map, La, scaling);
    gemm_fused<<<(NTOK / BM) * (D_OUT / BN), 256, 0, stream>>>(Xe, We, bias, out);
}

// Round 2
// 400.058 us; speedup vs baseline: 1.1593x; 1.1593x over previous
//
#include <hip/hip_runtime.h>
#include <hip/hip_bf16.h>

// Problem: out[n,o] = x[n,:] . W[o,:] + bias[o] + scale * sum_r (x[n,:].la[a,r,:]) * lb[a,o,:][r]
//          where a = lora_mapping[n]-1 (skip if mapping==0).
// Strategy: fold LoRA into the GEMM K-dim. Build bf16 Xe[16384,2176], We[2048,2176]
//   Xe[:,0:2048]=bf16(x); Xe[n,2048+(a*16+r)] = bf16(scale * x[n].la[a,r])  (one-hot in a)
//   We[:,0:2048]=bf16(W); We[o,2048+(a*16+r)] = bf16(lb[a,o,r])
// Then out = Xe @ We^T + bias — a single uniform bf16 MFMA GEMM, K=2176=34*64.
//
// R1: prep_x scalar+shuffle version latency-bound (154us).
// R2 FAILED: 16 parallel accumulators spilled to scratch -> 231us.
// R3: u via MFMA for ALL adapters, mask in epilogue. 456us total.
// R4 NEUTRAL: split prep into conv_all/ext_mfma/ext_w -> 464us. gemm unchanged
//   (143.5us); prep chain still ~320us by subtraction. ext_mfma kept the
//   latency-bound global-gather MFMA structure (16B/lane over 16 strided rows,
//   no staging); 5 serialized launches.
// R5 (this round): regime-pure consolidation, 5 kernels -> 3:
//   - conv_prep: ALL conversions (x, W, la, lb-ext) in one grid-stride
//     streaming pass. 229 MB coalesced float8->bf16x8.
//   - ext_gemm: u as a真 skinny GEMM (M=16384,N=128,K=2048) with the proven
//     gemm_fused machinery (global_load_lds w=16 + XOR swizzle + LDS MFMA).
//     BM=32/BN=128: wave w owns cols w*32..+31 (2 adapters, uniform mask).
//   - gemm_fused untouched (1007 TF effective; 256^2 8-phase is next).

#define D_IN   2048
#define D_OUT  2048
#define NTOK   16384
#define RANK   16
#define NADAPT 8
#define KEXT   2176          // 2048 + 8*16
#define BM     128
#define BN     128
#define BK     64
#define EBM    32            // ext_gemm M-tile

typedef __attribute__((ext_vector_type(8))) __bf16 bf16x8;
typedef __attribute__((ext_vector_type(8))) unsigned short u16x8;
typedef __attribute__((ext_vector_type(4))) float  f32x4;

__device__ inline unsigned short f2bf(float f) {
    unsigned u = __builtin_bit_cast(unsigned, f);
    u += 0x7fffu + ((u >> 16) & 1u);      // round-to-nearest-even
    return (unsigned short)(u >> 16);
}

// ---------------------------------------------------------------------------
// conv_prep: one streaming pass for every fp32->bf16 conversion.
// Unit = 8 contiguous elements (32B read, 16B write), all 16B-aligned:
//   seg0: x[16384][2048]  -> Xe base cols (KEXT row stride)
//   seg1: W[2048][2048]   -> We base cols
//   seg2: la[8][16][2048] -> La[128][2048] (contiguous)
//   seg3: lb[8][2048][16] -> We ext cols: We[o, 2048 + a*16 + r]; a unit of 8
//         ext cols (m=unit-in-row, a=m>>1, r=(m&1)*8) maps to 8 CONTIGUOUS
//         source floats lb[(a*2048+o)*16 + r .. +7].
// Branch is wave-uniform except at segment boundaries. 229 MB total.
// ---------------------------------------------------------------------------
#define SEG0 ((size_t)NTOK * 256)            // 4194304 units of x
#define SEG1 (SEG0 + (size_t)D_OUT * 256)    // + 524288 units of W
#define SEG2 (SEG1 + 32768)                  // + la units (8*16*2048/8)
#define TOTU (SEG2 + 32768)                  // + lb-ext units (2048*128/8)

__global__ void conv_prep(const float* __restrict__ x, const float* __restrict__ w,
                          const float* __restrict__ la, const float* __restrict__ lb,
                          unsigned short* __restrict__ Xe, unsigned short* __restrict__ We,
                          unsigned short* __restrict__ La) {
    size_t stride = (size_t)gridDim.x * 256;
    for (size_t u = (size_t)blockIdx.x * 256 + threadIdx.x; u < TOTU; u += stride) {
        const float* src;
        unsigned short* dst;
        if (u < SEG0) {
            int n = (int)(u >> 8), kc = ((int)u & 255) * 8;
            src = x + (size_t)n * D_IN + kc;
            dst = Xe + (size_t)n * KEXT + kc;
        } else if (u < SEG1) {
            size_t v = u - SEG0;
            int o = (int)(v >> 8), kc = ((int)v & 255) * 8;
            src = w + (size_t)o * D_IN + kc;
            dst = We + (size_t)o * KEXT + kc;
        } else if (u < SEG2) {
            size_t v = u - SEG1;
            src = la + v * 8;
            dst = La + v * 8;
        } else {
            size_t v = u - SEG2;
            int o = (int)(v >> 4), m = (int)v & 15;      // m = 8-col unit within ext row
            int a = m >> 1, r = (m & 1) * 8;
            src = lb + ((size_t)a * D_OUT + o) * RANK + r;
            dst = We + (size_t)o * KEXT + D_IN + m * 8;
        }
        float4 v0 = *(const float4*)(src);
        float4 v1 = *(const float4*)(src + 4);
        u16x8 s;
        s[0] = f2bf(v0.x); s[1] = f2bf(v0.y); s[2] = f2bf(v0.z); s[3] = f2bf(v0.w);
        s[4] = f2bf(v1.x); s[5] = f2bf(v1.y); s[6] = f2bf(v1.z); s[7] = f2bf(v1.w);
        *(u16x8*)dst = s;
    }
}

// ---------------------------------------------------------------------------
// ext_gemm: u[n][c] = Xb[n,:] . La[c,:], n in 32-token tiles, c = 0..127.
// Skinny GEMM with the gemm_fused structure: BM=32, BN=128, BK=64, 4 waves,
// wave w owns cols w*32..w*32+31 (adapters 2w, 2w+1 -> mask/scale wave-uniform).
// Staging via global_load_lds width=16 with XOR-swizzled source chunks
// (A: 256 chunks = 1/thread; B: 1024 chunks = 4/thread). B (La, 512 KB) is
// L2-hot across all 512 blocks. Epilogue masks by map[token], scales, writes
// Xe ext cols (reads base cols / writes ext cols: disjoint, no hazard).
// u C-layout: col=lane&15 (ext col), row=(lane>>4)*4+reg (token) [m89-verified].
// ---------------------------------------------------------------------------
__global__ void ext_gemm(unsigned short* Xe, const int* __restrict__ map,
                         const unsigned short* __restrict__ La,
                         const float* __restrict__ scaling) {
    __shared__ unsigned short As[EBM * BK];              // 4 KB
    __shared__ unsigned short Bs[128 * BK];              // 16 KB

    int t = threadIdx.x, lane = t & 63, wave = t >> 6;
    int n0 = blockIdx.x * EBM;

    f32x4 acc[2][2] = {};

    for (int k0 = 0; k0 < D_IN; k0 += BK) {
        __syncthreads();
        {   // A tile: 32 rows x 8 chunks, one 16B chunk per thread
            int row = t >> 3, kc = t & 7, gc = kc ^ (row & 7);
            const unsigned short* ga = Xe + (size_t)(n0 + row) * KEXT + k0 + gc * 8;
            __builtin_amdgcn_global_load_lds(
                (const __attribute__((address_space(1))) unsigned int*)ga,
                (__attribute__((address_space(3))) unsigned int*)(As + wave * 512),
                16, 0, 0);
        }
#pragma unroll
        for (int c = 0; c < 4; ++c) {                    // B tile: 128 rows x 8 chunks
            int linear = (wave * 4 + c) * 64 + lane;
            int row = linear >> 3, kc = linear & 7, gc = kc ^ (row & 7);
            const unsigned short* gb = La + (size_t)row * D_IN + k0 + gc * 8;
            __builtin_amdgcn_global_load_lds(
                (const __attribute__((address_space(1))) unsigned int*)gb,
                (__attribute__((address_space(3))) unsigned int*)(Bs + (wave * 4 + c) * 512),
                16, 0, 0);
        }
        __syncthreads();
#pragma unroll
        for (int ks = 0; ks < 2; ++ks) {
            int gchunk = ks * 4 + (lane >> 4);
            int sw = gchunk ^ (lane & 7);                // row&7 == lane&7 (16-aligned tiles)
            bf16x8 af[2], bfr[2];
#pragma unroll
            for (int i = 0; i < 2; ++i)
                af[i] = *(const bf16x8*)(As + (i * 16 + (lane & 15)) * BK + sw * 8);
#pragma unroll
            for (int j = 0; j < 2; ++j)
                bfr[j] = *(const bf16x8*)(Bs + (wave * 32 + j * 16 + (lane & 15)) * BK + sw * 8);
#pragma unroll
            for (int i = 0; i < 2; ++i)
#pragma unroll
                for (int j = 0; j < 2; ++j)
                    acc[i][j] = __builtin_amdgcn_mfma_f32_16x16x32_bf16(af[i], bfr[j], acc[i][j], 0, 0, 0);
        }
    }

    // epilogue: c = wave*32 + j*16 + (lane&15) -> adapter a = wave*2 + j (uniform)
    int colq = lane & 15, rq = lane >> 4;
#pragma unroll
    for (int j = 0; j < 2; ++j) {
        int c = wave * 32 + j * 16 + colq;
        int aid = wave * 2 + j + 1;
        float sc = scaling[wave * 2 + j];
#pragma unroll
        for (int i = 0; i < 2; ++i) {
#pragma unroll
            for (int r = 0; r < 4; ++r) {
                int token = n0 + i * 16 + rq * 4 + r;
                unsigned short v = 0;
                if (map[token] == aid) v = f2bf(acc[i][j][r] * sc);
                Xe[(size_t)token * KEXT + D_IN + c] = v;
            }
        }
    }
}

// ---------------------------------------------------------------------------
// Main GEMM: out[M=16384, N=2048] = Xe @ We^T + bias.  m97 structure:
// 128x128 tile, BK=64, 4 waves in 2x2, each wave 64x64 via 4x4 of 16x16x32
// bf16 MFMA, global_load_lds width=16 staging, XOR-swizzled LDS k-chunks
// (swizzle applied on the global source address so the wave-uniform LDS
// destination stays contiguous — required by global_load_lds semantics).
// ---------------------------------------------------------------------------
__global__ void gemm_fused(const unsigned short* __restrict__ Xe,
                           const unsigned short* __restrict__ We,
                           const float* __restrict__ bias,
                           float* __restrict__ out) {
    __shared__ unsigned short As[BM * BK];               // [128][64] bf16, 16 KB
    __shared__ unsigned short Bs[BN * BK];

    int t = threadIdx.x;
    int lane = t & 63, wave = t >> 6;
    // supertile swizzle: groups of 8 row-tiles x 16 col-tiles for L2 locality
    int g = blockIdx.x;
    int group = g >> 7, within = g & 127;
    int bm = group * 8 + (within & 7);                   // 0..127
    int bn = within >> 3;                                // 0..15

    int wm = wave >> 1, wn = wave & 1;                   // 2x2 wave grid
    f32x4 acc[4][4] = {};

    for (int k0 = 0; k0 < KEXT; k0 += BK) {
        __syncthreads();                                 // prev compute done
#pragma unroll
        for (int c = 0; c < 4; ++c) {
            int linear = (wave * 4 + c) * 64 + lane;     // 16B-chunk id within tile
            int row = linear >> 3;                       // 0..127
            int kc  = linear & 7;                        // 16B chunk within row
            int gc  = kc ^ (row & 7);                    // fetch swizzled source chunk
            const unsigned short* ga = Xe + (size_t)(bm * BM + row) * KEXT + k0 + gc * 8;
            __builtin_amdgcn_global_load_lds(
                (const __attribute__((address_space(1))) unsigned int*)ga,
                (__attribute__((address_space(3))) unsigned int*)(As + (wave * 4 + c) * 512),
                16, 0, 0);
            const unsigned short* gb = We + (size_t)(bn * BN + row) * KEXT + k0 + gc * 8;
            __builtin_amdgcn_global_load_lds(
                (const __attribute__((address_space(1))) unsigned int*)gb,
                (__attribute__((address_space(3))) unsigned int*)(Bs + (wave * 4 + c) * 512),
                16, 0, 0);
        }
        __syncthreads();                                 // staging visible (compiler drains vmcnt)
#pragma unroll
        for (int ks = 0; ks < 2; ++ks) {                 // two K=32 steps per BK=64
            bf16x8 af[4], bfr[4];
            int gchunk = ks * 4 + (lane >> 4);
            int sw = gchunk ^ (lane & 7);                // row&7 == lane&7 for 16-aligned tiles
#pragma unroll
            for (int i = 0; i < 4; ++i) {
                int rowA = wm * 64 + i * 16 + (lane & 15);
                af[i]  = *(const bf16x8*)(As + rowA * BK + sw * 8);
                int rowB = wn * 64 + i * 16 + (lane & 15);
                bfr[i] = *(const bf16x8*)(Bs + rowB * BK + sw * 8);
            }
#pragma unroll
            for (int i = 0; i < 4; ++i)
#pragma unroll
                for (int j = 0; j < 4; ++j)
                    acc[i][j] = __builtin_amdgcn_mfma_f32_16x16x32_bf16(af[i], bfr[j], acc[i][j], 0, 0, 0);
        }
    }

    // epilogue: C/D layout col=lane&15, row=(lane>>4)*4+reg  [m89-verified]
    int colq = lane & 15, rq = lane >> 4;
#pragma unroll
    for (int j = 0; j < 4; ++j) {
        int col = bn * BN + wn * 64 + j * 16 + colq;
        float bv = bias[col];
#pragma unroll
        for (int i = 0; i < 4; ++i) {
            int row0 = bm * BM + wm * 64 + i * 16 + rq * 4;
#pragma unroll
            for (int r = 0; r < 4; ++r)
                out[(size_t)(row0 + r) * D_OUT + col] = acc[i][j][r] + bv;
        }
    }
}

extern "C" void kernel_launch(void* const* d_in, const int* in_sizes, int n_in,
                              void* d_out, int out_size, void* d_ws, size_t ws_size,
                              hipStream_t stream) {
    (void)in_sizes; (void)n_in; (void)out_size; (void)ws_size;
    const float* x       = (const float*)d_in[0];
    const int*   map     = (const int*)d_in[1];
    const float* weight  = (const float*)d_in[2];
    const float* bias    = (const float*)d_in[3];
    const float* lora_a  = (const float*)d_in[4];
    const float* lora_b  = (const float*)d_in[5];
    const float* scaling = (const float*)d_in[6];
    float* out = (float*)d_out;

    unsigned short* Xe = (unsigned short*)d_ws;                    // 16384*2176*2 = 71.3 MB
    unsigned short* We = Xe + (size_t)NTOK * KEXT;                 // + 8.9 MB
    unsigned short* La = We + (size_t)D_OUT * KEXT;                // + 0.5 MB bf16 [128][2048]

    conv_prep<<<2048, 256, 0, stream>>>(x, weight, lora_a, lora_b, Xe, We, La);
    ext_gemm<<<NTOK / EBM, 256, 0, stream>>>(Xe, map, La, scaling);
    gemm_fused<<<(NTOK / BM) * (D_OUT / BN), 256, 0, stream>>>(Xe, We, bias, out);
}